// Round 1
// 451.919 us; speedup vs baseline: 1.0011x; 1.0011x over previous
//
#include <hip/hip_runtime.h>
#include <math.h>

#define HORIZON 20
#define NCLASS  36
constexpr float STEP = 2.0f;
constexpr float TWO_PI_OVER_C = 0.17453292519943295f; // 2*pi/36
constexpr float OBS_RADIUS = 1.0f;
// VEH_RADIUS = 2.0 -> compare d^2 < 4.0

#define NODES_PER_BLOCK 16
#define ROWS_PER_BLOCK  (NODES_PER_BLOCK * HORIZON)   // 320
#define FUSED_BS        320                           // 5 waves

// Per-block (sum,count) reduction -> non-atomic partial store.
// ALL threads of the block must call this (no early returns before it).
template <int BS>
__device__ __forceinline__ void block_commit(float sum, unsigned cnt,
                                             float* __restrict__ pOut,
                                             unsigned* __restrict__ cOut,
                                             int slot) {
    __shared__ float    ls[BS / 64];
    __shared__ unsigned lc[BS / 64];
    #pragma unroll
    for (int off = 32; off > 0; off >>= 1) {
        sum += __shfl_down(sum, off, 64);
        cnt += __shfl_down(cnt, off, 64);
    }
    int wid = threadIdx.x >> 6;
    if ((threadIdx.x & 63) == 0) { ls[wid] = sum; lc[wid] = cnt; }
    __syncthreads();
    if (threadIdx.x == 0) {
        float s = 0.0f; unsigned c = 0u;
        #pragma unroll
        for (int w = 0; w < BS / 64; w++) { s += ls[w]; c += lc[w]; }
        pOut[slot] = s;
        cOut[slot] = c;
    }
}

// Fused kernel: class decode (coalesced pred reads) + per-node cumsum rollout
// + vehicle masking + distance partials + obstacle source packing.
// Block = 320 threads (5 waves) = exactly 16 nodes = 320 (node,h) rows.
// Wave w handles rows [blk*320 + w*64, +64): 9 float4 loads/lane = 1 KB/wave-inst.
// Per-float4 (max,idx) partials go to LDS (stride 9 floats, odd -> lane l and
// l+32 alias the same bank = 2-way, free). Thread t reduces row t's 9 partials
// in ascending class order (strict > == first argmax) -> step vec in LDS.
// Threads 0..15 do the sequential cumsum for their node into LDS; 160 threads
// then write traj out as coalesced float4. Eliminates the steps global
// round-trip (32 MB) and one dispatch vs the split version.
__global__ void __launch_bounds__(FUSED_BS) fused_rollout_kernel(
        const float* __restrict__ X,
        const float* __restrict__ pred,
        float2* __restrict__ traj,
        float4* __restrict__ obsInfo,
        float* __restrict__ distP,
        unsigned* __restrict__ distC,
        int n_nodes) {
    __shared__ float smM[5][576];
    __shared__ float smI[5][576];
    __shared__ __align__(16) float2 smSteps[ROWS_PER_BLOCK];
    __shared__ __align__(16) float2 smTraj[ROWS_PER_BLOCK];

    int total_rows = n_nodes * HORIZON;
    int total_f4 = total_rows * 9;
    int wave = threadIdx.x >> 6;
    int lane = threadIdx.x & 63;
    int block_row0 = blockIdx.x * ROWS_PER_BLOCK;
    int row0 = block_row0 + wave * 64;

    const float4* p4 = (const float4*)pred;
    #pragma unroll
    for (int q = 0; q < 9; q++) {
        int gl = q * 64 + lane;          // 0..575 within the wave's chunk
        int g = row0 * 9 + gl;           // global float4 index
        float4 v;
        if (g < total_f4) v = p4[g];
        else v = make_float4(-INFINITY, -INFINITY, -INFINITY, -INFINITY);
        int j = gl % 9;                  // float4 position within its row
        float m = v.x; int ii = 0;
        if (v.y > m) { m = v.y; ii = 1; }
        if (v.z > m) { m = v.z; ii = 2; }
        if (v.w > m) { m = v.w; ii = 3; }
        smM[wave][gl] = m;
        smI[wave][gl] = (float)(j * 4 + ii);
    }
    __syncthreads();

    // per-row argmax reduce + angle -> step vector (one row per thread)
    {
        float best = -INFINITY; float bidx = 0.0f;
        #pragma unroll
        for (int j = 0; j < 9; j++) {
            float m = smM[wave][lane * 9 + j];
            float id = smI[wave][lane * 9 + j];
            if (m > best) { best = m; bidx = id; }   // ascending j: first wins
        }
        float ang = bidx * TWO_PI_OVER_C * best;
        float s, c;
        sincosf(ang, &s, &c);
        smSteps[threadIdx.x] = make_float2(STEP * c, STEP * s);
    }
    __syncthreads();

    // sequential rollout: one thread per node (16 active), short loop
    float dsum = 0.0f;
    unsigned vehc = 0u;
    if (threadIdx.x < NODES_PER_BLOCK) {
        int g = blockIdx.x * NODES_PER_BLOCK + threadIdx.x;
        if (g < n_nodes) {
            const float* xr = X + (size_t)g * 5;
            float typ = xr[0];
            float px = xr[1], py = xr[2];
            float tx = xr[3], ty = xr[4];
            float thr = tx + OBS_RADIUS;       // X[:,3] doubles as obstacle radius
            obsInfo[g] = make_float4(px, py, (thr > 0.0f) ? thr * thr : -1.0f, 0.0f);
            bool veh = (typ == 0.0f);
            #pragma unroll
            for (int h = 0; h < HORIZON; h++) {
                float2 st = smSteps[threadIdx.x * HORIZON + h];
                px += st.x; py += st.y;
                float ox = veh ? px : 0.0f;
                float oy = veh ? py : 0.0f;
                smTraj[threadIdx.x * HORIZON + h] = make_float2(ox, oy);
                float dx = tx - ox, dy = ty - oy;
                dsum += veh ? sqrtf(fmaf(dy, dy, dx * dx)) : 0.0f;
            }
            vehc = veh ? 1u : 0u;
        }
    }
    __syncthreads();

    // coalesced traj write-out: 160 float4 per full block
    int rows_in_blk = min(ROWS_PER_BLOCK, total_rows - block_row0);
    if (rows_in_blk == ROWS_PER_BLOCK) {
        if (threadIdx.x < ROWS_PER_BLOCK / 2) {
            ((float4*)(traj + block_row0))[threadIdx.x] =
                ((const float4*)smTraj)[threadIdx.x];
        }
    } else {
        for (int r = threadIdx.x; r < rows_in_blk; r += FUSED_BS)
            traj[block_row0 + r] = smTraj[r];
    }

    block_commit<FUSED_BS>(dsum, vehc, distP, distC, blockIdx.x);
}

// Edges kernel (fused): obstacle edges on blocks [0, nbO), vehicle edges on
// blocks [nbO, nbO+nbV). Vehicle path: 2 threads/edge; each thread loads only
// its HALF of both trajectories (5+5 float4 = 160 B vs 240 B before) and
// reconstructs the full b-trajectory from its lane-pair partner via
// __shfl_xor(.,1). All register arrays constant-indexed -> no scratch.
__global__ void __launch_bounds__(256) edges_kernel(const float4* __restrict__ obsInfo,
                                                    const int* __restrict__ eo, int mo,
                                                    const int* __restrict__ ev, int mv,
                                                    const float2* __restrict__ traj,
                                                    float* __restrict__ obsP,
                                                    unsigned* __restrict__ obsC,
                                                    float* __restrict__ vehP,
                                                    unsigned* __restrict__ vehC,
                                                    int nbO) {
    if ((int)blockIdx.x < nbO) {
        // ---- obstacle path ----
        int e = blockIdx.x * 256 + threadIdx.x;
        float osum = 0.0f; unsigned ocnt = 0;
        if (e < mo) {
            int src = eo[e];
            int dst = eo[mo + e];
            float4 info = obsInfo[src];          // (x, y, thr2 or -1, 0)
            if (info.z >= 0.0f) {                // thr<=0 lanes skip the gather
                const float4* tp = (const float4*)(traj + (size_t)dst * HORIZON);
                float4 buf[10];
                #pragma unroll
                for (int q = 0; q < 10; q++) buf[q] = tp[q];
                const float* f = (const float*)buf;
                #pragma unroll
                for (int h = 0; h < HORIZON; h++) {
                    float dx = info.x - f[2 * h], dy = info.y - f[2 * h + 1];
                    float d2 = fmaf(dy, dy, dx * dx);
                    bool near = d2 < info.z;
                    ocnt += near ? 1u : 0u;
                    osum += near ? rsqrtf(d2) : 0.0f;
                }
            }
        }
        block_commit<256>(osum, ocnt, obsP, obsC, blockIdx.x);
    } else {
        // ---- vehicle path: 2 threads per edge, pair-shared b-trajectory ----
        int t = (blockIdx.x - nbO) * 256 + threadIdx.x;
        int e = t >> 1;
        int half = t & 1;
        float vsum = 0.0f; unsigned vcnt = 0;
        if (e < mv) {                            // pair-uniform guard
            int a = ev[e];
            int b = ev[mv + e];
            const float4* pa = (const float4*)(traj + (size_t)a * HORIZON + half * 10);
            const float4* pb = (const float4*)(traj + (size_t)b * HORIZON + half * 10);
            float4 ta[5], tbh[5];
            #pragma unroll
            for (int q = 0; q < 5; q++) { ta[q] = pa[q]; tbh[q] = pb[q]; }
            // build full b-trajectory: own half + partner's half (shfl_xor 1)
            float fb[40];
            const float* ft = (const float*)tbh;
            #pragma unroll
            for (int k = 0; k < 20; k++) {
                float other = __shfl_xor(ft[k], 1, 64);
                fb[k]      = (half == 0) ? ft[k] : other;  // points 0..9
                fb[20 + k] = (half == 0) ? other : ft[k];  // points 10..19
            }
            const float* fa = (const float*)ta;
            #pragma unroll
            for (int i = 0; i < 10; i++) {
                float ax = fa[2 * i], ay = fa[2 * i + 1];
                #pragma unroll
                for (int j = 0; j < HORIZON; j++) {
                    float dx = ax - fb[2 * j];
                    float dy = ay - fb[2 * j + 1];
                    float d2 = fmaf(dy, dy, dx * dx);
                    bool near = d2 < 4.0f;             // vd < 2  <=>  d2 < 4
                    vcnt += near ? 1u : 0u;
                    vsum += near ? rsqrtf(d2) : 0.0f;  // 1/vd
                }
            }
        }
        block_commit<256>(vsum, vcnt, vehP, vehC, blockIdx.x - nbO);
    }
}

// Finalize: reduce all block partials (double precision) -> 4 outputs.
__global__ void __launch_bounds__(256) finalize_kernel(
        const float* __restrict__ distP, const unsigned* __restrict__ distC, int nbR,
        const float* __restrict__ obsP,  const unsigned* __restrict__ obsC,  int nbO,
        const float* __restrict__ vehP,  const unsigned* __restrict__ vehC,  int nbV,
        float* __restrict__ out) {
    double s0 = 0, s1 = 0, s2 = 0;
    unsigned long long c0 = 0, c1 = 0, c2 = 0;
    for (int i = threadIdx.x; i < nbR; i += 256) { s0 += (double)distP[i]; c0 += distC[i]; }
    for (int i = threadIdx.x; i < nbO; i += 256) { s1 += (double)obsP[i];  c1 += obsC[i]; }
    for (int i = threadIdx.x; i < nbV; i += 256) { s2 += (double)vehP[i];  c2 += vehC[i]; }
    __shared__ double ds[3][4];
    __shared__ unsigned long long dc[3][4];
    double sv[3] = {s0, s1, s2};
    unsigned long long cv[3] = {c0, c1, c2};
    #pragma unroll
    for (int k = 0; k < 3; k++) {
        double v = sv[k]; unsigned long long cc = cv[k];
        #pragma unroll
        for (int off = 32; off > 0; off >>= 1) {
            v += __shfl_down(v, off, 64);
            cc += __shfl_down(cc, off, 64);
        }
        if ((threadIdx.x & 63) == 0) { ds[k][threadIdx.x >> 6] = v; dc[k][threadIdx.x >> 6] = cc; }
    }
    __syncthreads();
    if (threadIdx.x == 0) {
        double S[3]; unsigned long long C[3];
        #pragma unroll
        for (int k = 0; k < 3; k++) {
            S[k] = ds[k][0] + ds[k][1] + ds[k][2] + ds[k][3];
            C[k] = dc[k][0] + dc[k][1] + dc[k][2] + dc[k][3];
        }
        float dist = (C[0] > 0) ? (float)(S[0] / ((double)C[0] * (double)HORIZON)) : 0.0f;
        float obs  = (C[1] > 0) ? (float)(S[1] / (double)C[1]) : 0.0f;
        float veh  = (C[2] > 0) ? (float)(S[2] / (double)C[2]) : 0.0f;
        out[0] = dist + obs + veh;
        out[1] = dist;
        out[2] = obs;
        out[3] = veh;
    }
}

extern "C" void kernel_launch(void* const* d_in, const int* in_sizes, int n_in,
                              void* d_out, int out_size, void* d_ws, size_t ws_size,
                              hipStream_t stream) {
    const float* X    = (const float*)d_in[0];
    const float* pred = (const float*)d_in[1];
    const int*   ev   = (const int*)d_in[2];
    const int*   eo   = (const int*)d_in[3];
    int n_nodes = in_sizes[0] / 5;
    int mv = in_sizes[2] / 2;
    int mo = in_sizes[3] / 2;

    int total_rows = n_nodes * HORIZON;              // 2,000,000
    int nbF = (n_nodes + NODES_PER_BLOCK - 1) / NODES_PER_BLOCK;   // 6250
    int nbO = (mo + 255) / 256;
    int nbV = (2 * mv + 255) / 256;

    char* w = (char*)d_ws;
    size_t off = 0;
    float2* traj = (float2*)(w + off);
    off += (size_t)total_rows * sizeof(float2);
    off = (off + 255) & ~(size_t)255;
    float4* obsInfo = (float4*)(w + off);   off += (size_t)n_nodes * sizeof(float4);
    off = (off + 255) & ~(size_t)255;
    float*    distP = (float*)(w + off);    off += (size_t)nbF * 4;
    unsigned* distC = (unsigned*)(w + off); off += (size_t)nbF * 4;
    float*    obsP  = (float*)(w + off);    off += (size_t)nbO * 4;
    unsigned* obsC  = (unsigned*)(w + off); off += (size_t)nbO * 4;
    float*    vehP  = (float*)(w + off);    off += (size_t)nbV * 4;
    unsigned* vehC  = (unsigned*)(w + off); off += (size_t)nbV * 4;
    float* out = (float*)d_out;

    hipLaunchKernelGGL(fused_rollout_kernel, dim3(nbF), dim3(FUSED_BS), 0, stream,
                       X, pred, traj, obsInfo, distP, distC, n_nodes);
    hipLaunchKernelGGL(edges_kernel, dim3(nbO + nbV), dim3(256), 0, stream,
                       obsInfo, eo, mo, ev, mv, traj, obsP, obsC, vehP, vehC, nbO);
    hipLaunchKernelGGL(finalize_kernel, dim3(1), dim3(256), 0, stream,
                       distP, distC, nbF, obsP, obsC, nbO, vehP, vehC, nbV, out);
}